// Round 2
// baseline (273.474 us; speedup 1.0000x reference)
//
#include <hip/hip_runtime.h>
#include <hip/hip_bf16.h>

// DecoderConv: weighted conv1d (B=8, Cin=Cout=256, L=16384, K=9) + BatchNorm(train) + ReLU
// y[b,o,l] = sum_{c,kk} W[o,c,kk] * x[b,c,l+kk-4] * w[b,kk,l],  w = gaussian coord weight
// Correctness-first structure (verified m91/m97 fragment pattern only):
//   k_prep : conv_w -> bf16 Aperm[kk][o][c], zero stats
//   k_w    : w[b][kk][l]
//   k_gemm : block 256o x 256l, 8 waves (2x4) of 128o x 64l, K-chunk 64c x 9kk.
//            Ash[o][c] (padded 72) and Xsh[l'][c] (padded 72, bf16 x transposed once
//            per c-chunk, shared by all 9 taps). Both fragments are contiguous
//            ds_read_b128 with identical k-maps. Gaussian w applied per-lane on B-frag.
//            Epilogue: +conv_b, raw y to d_out, per-channel sum/sumsq atomics.
//   k_norm : in-place batchnorm+relu on d_out.

typedef float        f32x4  __attribute__((ext_vector_type(4)));
typedef short        bf16x8 __attribute__((ext_vector_type(8)));
typedef unsigned int u32x4  __attribute__((ext_vector_type(4)));

#define LLEN 16384

__device__ __forceinline__ unsigned short bf16bits(float a) {
  return __builtin_bit_cast(unsigned short, __float2bfloat16(a));
}
__device__ __forceinline__ unsigned packbf(float a, float b) {
  return (unsigned)bf16bits(a) | ((unsigned)bf16bits(b) << 16);
}

// ================= k_prep: Aperm[kk][o][c] + zero sums =================
__global__ void k_prep(const float* __restrict__ cw,
                       unsigned short* __restrict__ Aperm,
                       float* __restrict__ sums) {
  const int idx = blockIdx.x * 256 + threadIdx.x;  // 2304*256 = 256*256*9 exactly
  if (idx < 512) sums[idx] = 0.0f;
  const int o   = idx / 2304;
  const int rem = idx - o * 2304;
  const int c   = rem / 9;
  const int kk  = rem - c * 9;
  Aperm[((size_t)kk * 256 + o) * 256 + c] = bf16bits(cw[idx]);
}

// ================= k_w: gaussian weights w[b][kk][l] =================
__global__ void k_w(const float* __restrict__ coords, float* __restrict__ wbuf) {
  const int gidx = blockIdx.x * 256 + threadIdx.x;  // = b*L + l
  const int b = gidx >> 14, l = gidx & (LLEN - 1);
  const float* cb = coords + (size_t)b * 3 * LLEN;
  const float c0 = cb[l], c1 = cb[LLEN + l], c2v = cb[2 * LLEN + l];
#pragma unroll
  for (int kk = 0; kk < 9; ++kk) {
    const int lc = l + kk - 4;
    float a0 = 0.f, a1 = 0.f, a2 = 0.f;
    if (lc >= 0 && lc < LLEN) { a0 = cb[lc]; a1 = cb[LLEN + lc]; a2 = cb[2 * LLEN + lc]; }
    const float d0 = a0 - c0, d1 = a1 - c1, d2 = a2 - c2v;
    wbuf[(((size_t)(b * 9 + kk)) << 14) + l] = __expf(-0.5f * (d0 * d0 + d1 * d1 + d2 * d2));
  }
}

// ================= k_gemm =================
__global__ __launch_bounds__(512, 2) void k_gemm(
    const float* __restrict__ x, const float* __restrict__ wbuf,
    const unsigned short* __restrict__ Aperm, const float* __restrict__ convb,
    float* __restrict__ y, float* __restrict__ sums) {
  __shared__ __align__(16) unsigned short Ash[256][72];  // conv weights [o][c], pad->144B rows
  __shared__ __align__(16) unsigned short Xsh[264][72];  // x^T tile [l'][c], l' = l0-4+row

  const int tid  = threadIdx.x;
  const int lane = tid & 63, wv = tid >> 6;
  const int wm = wv >> 2, wn = wv & 3;          // 2 x 4 waves
  const int hi = lane >> 4, lo16 = lane & 15;
  const int b  = blockIdx.x >> 6, lt = blockIdx.x & 63;
  const int l0 = lt << 8;

  f32x4 acc[8][4];
#pragma unroll
  for (int i = 0; i < 8; ++i)
#pragma unroll
    for (int j = 0; j < 4; ++j) acc[i][j] = f32x4{0.f, 0.f, 0.f, 0.f};

  const int arow  = tid >> 3;        // 0..63
  const int acol8 = (tid & 7) * 8;   // 0..56
  const int nbase = wn * 64 + lo16;  // block-local l for this thread's B frags (+nt*16)

  u32x4 ar[4];
  float wl[4], wln[4];

  // initial A + w prefetch (kk=0, cc=0)
#pragma unroll
  for (int p = 0; p < 4; ++p)
    ar[p] = *reinterpret_cast<const u32x4*>(
        Aperm + ((size_t)(p * 64 + arow)) * 256 + acol8);
#pragma unroll
  for (int nt = 0; nt < 4; ++nt)
    wl[nt] = wbuf[((size_t)(b * 9) << 14) + l0 + nbase + nt * 16];

#pragma unroll 1
  for (int cc = 0; cc < 4; ++cc) {
    __syncthreads();  // previous step's readers of Ash/Xsh are done
    // ---- stage Xsh: bf16 transpose of x tile, rows l' = l0-4 .. l0+259 ----
    {
      const int c = tid >> 3, rg = tid & 7;
      const float* xrow = x + ((size_t)(b * 256 + cc * 64 + c)) * LLEN;
#pragma unroll 1
      for (int grp = rg; grp < 66; grp += 8) {
        const int lx = l0 - 4 + grp * 4;
        f32x4 v;
        if (lx >= 0 && lx <= LLEN - 4) {
          v = *reinterpret_cast<const f32x4*>(xrow + lx);
        } else {
#pragma unroll
          for (int q = 0; q < 4; ++q) {
            const int lq = lx + q;
            v[q] = (lq >= 0 && lq < LLEN) ? xrow[lq] : 0.f;
          }
        }
#pragma unroll
        for (int q = 0; q < 4; ++q) Xsh[grp * 4 + q][c] = bf16bits(v[q]);
      }
    }
#pragma unroll 1
    for (int kk = 0; kk < 9; ++kk) {
      if (kk) __syncthreads();
      // ---- write Ash from prefetched regs ----
#pragma unroll
      for (int p = 0; p < 4; ++p)
        *reinterpret_cast<u32x4*>(reinterpret_cast<char*>(&Ash[0][0]) +
                                  (p * 64 + arow) * 144 + acol8 * 2) = ar[p];
      // ---- prefetch next step's A + w ----
      int nkk = kk + 1, ncc = cc;
      if (nkk == 9) { nkk = 0; ++ncc; if (ncc == 4) { ncc = 3; nkk = 8; } }
#pragma unroll
      for (int p = 0; p < 4; ++p)
        ar[p] = *reinterpret_cast<const u32x4*>(
            Aperm + ((size_t)nkk * 256 + p * 64 + arow) * 256 + ncc * 64 + acol8);
#pragma unroll
      for (int nt = 0; nt < 4; ++nt)
        wln[nt] = wbuf[((size_t)(b * 9 + nkk) << 14) + l0 + nbase + nt * 16];
      __syncthreads();  // staging visible
      // ---- compute: 2 k-halves of this 64c chunk ----
#pragma unroll
      for (int kb = 0; kb < 2; ++kb) {
        bf16x8 bfrag[4];
#pragma unroll
        for (int nt = 0; nt < 4; ++nt) {
          const int r = nbase + nt * 16 + kk;  // Xsh row = block-l + kk
          const u32x4 xr = *reinterpret_cast<const u32x4*>(
              reinterpret_cast<const char*>(&Xsh[0][0]) + r * 144 + kb * 64 + hi * 16);
          const float wv2 = wl[nt];
          u32x4 o4;
#pragma unroll
          for (int q = 0; q < 4; ++q) {
            const unsigned u = xr[q];
            const float flo = __builtin_bit_cast(float, u << 16) * wv2;
            const float fhi = __builtin_bit_cast(float, u & 0xffff0000u) * wv2;
            o4[q] = packbf(flo, fhi);
          }
          bfrag[nt] = __builtin_bit_cast(bf16x8, o4);
        }
#pragma unroll
        for (int mt = 0; mt < 8; ++mt) {
          const int orow = wm * 128 + mt * 16 + lo16;
          const bf16x8 af = *reinterpret_cast<const bf16x8*>(
              reinterpret_cast<const char*>(&Ash[0][0]) + orow * 144 + kb * 64 + hi * 16);
#pragma unroll
          for (int nt = 0; nt < 4; ++nt)
            acc[mt][nt] = __builtin_amdgcn_mfma_f32_16x16x32_bf16(af, bfrag[nt],
                                                                  acc[mt][nt], 0, 0, 0);
        }
      }
#pragma unroll
      for (int nt = 0; nt < 4; ++nt) wl[nt] = wln[nt];
    }
  }

  // ---- epilogue: +conv_b, raw y store, per-channel sums ----
  __syncthreads();
  float* red = reinterpret_cast<float*>(&Ash[0][0]);  // 512 floats
  red[tid] = 0.0f;
  __syncthreads();
#pragma unroll
  for (int mt = 0; mt < 8; ++mt) {
#pragma unroll
    for (int v = 0; v < 4; ++v) {
      const int o = wm * 128 + mt * 16 + hi * 4 + v;  // C/D: row = hi*4 + reg
      const float cb = convb[o];
      float s = 0.f, s2 = 0.f;
#pragma unroll
      for (int nt = 0; nt < 4; ++nt) {
        const int l = l0 + nbase + nt * 16;           // C/D: col = lo16
        const float yv = acc[mt][nt][v] + cb;
        y[(((size_t)b * 256 + o) << 14) + l] = yv;
        s += yv; s2 += yv * yv;
      }
#pragma unroll
      for (int d = 1; d < 16; d <<= 1) { s += __shfl_xor(s, d); s2 += __shfl_xor(s2, d); }
      if (lo16 == 0) { atomicAdd(&red[o], s); atomicAdd(&red[o + 256], s2); }
    }
  }
  __syncthreads();
  atomicAdd(&sums[tid], red[tid]);
}

// ================= k_norm: batchnorm + relu, in place on d_out =================
__global__ void k_norm(float* __restrict__ y, const float* __restrict__ sums,
                       const float* __restrict__ gamma, const float* __restrict__ beta) {
  const size_t i0 = ((size_t)blockIdx.x * 256 + threadIdx.x) * 8;
  const int o = (int)((i0 >> 14) & 255);
  const float n = 131072.f;  // B*L
  const float mu = sums[o] / n;
  float var = sums[256 + o] / n - mu * mu;
  var = fmaxf(var, 0.f);
  const float sc = rsqrtf(var + 1e-5f) * gamma[o];
  const float bb = beta[o] - mu * sc;
  f32x4 v0 = *reinterpret_cast<const f32x4*>(y + i0);
  f32x4 v1 = *reinterpret_cast<const f32x4*>(y + i0 + 4);
#pragma unroll
  for (int i = 0; i < 4; ++i) {
    v0[i] = fmaxf(v0[i] * sc + bb, 0.f);
    v1[i] = fmaxf(v1[i] * sc + bb, 0.f);
  }
  *reinterpret_cast<f32x4*>(y + i0) = v0;
  *reinterpret_cast<f32x4*>(y + i0 + 4) = v1;
}

// ================= launch =================
extern "C" void kernel_launch(void* const* d_in, const int* in_sizes, int n_in,
                              void* d_out, int out_size, void* d_ws, size_t ws_size,
                              hipStream_t stream) {
  const float* x      = (const float*)d_in[0];
  const float* coords = (const float*)d_in[1];
  const float* conv_w = (const float*)d_in[2];
  const float* conv_b = (const float*)d_in[3];
  const float* gamma  = (const float*)d_in[4];
  const float* beta   = (const float*)d_in[5];
  float* out = (float*)d_out;

  float* sums = (float*)d_ws;                          // 512 f32
  float* wbuf = (float*)((char*)d_ws + 4096);          // 8*9*16384 f32 = 4.72MB
  unsigned short* Aperm =
      (unsigned short*)((char*)d_ws + 4096 + (size_t)8 * 9 * LLEN * 4);  // 9*256*256 bf16

  k_prep<<<2304, 256, 0, stream>>>(conv_w, Aperm, sums);
  k_w<<<512, 256, 0, stream>>>(coords, wbuf);
  k_gemm<<<512, 512, 0, stream>>>(x, wbuf, Aperm, conv_b, out, sums);
  k_norm<<<16384, 256, 0, stream>>>(out, sums, gamma, beta);
}